// Round 5
// baseline (121.036 us; speedup 1.0000x reference)
//
#include <hip/hip_runtime.h>
#include <math.h>

// EnhancedTripletLoss, B=8192, D=256, 8 classes.
// R21: overhead round. Profile showed top-5 dispatches are the harness's
// 256 MiB workspace re-poison fills (~42 us, fixed). Attack the controllable
// rest:
//  - k_hist+k_perm fused into one single-block k_sort (shfl-scan stable
//    counting sort), one launch fewer.
//  - Slot count 128 -> 64 (slot = opposite block id). i-side combines the two
//    wj-waves via LDS before publishing slot bj; j-side combines wi-pairs and
//    publishes slot bi. Partial traffic halves; k_finish slot loop 16 -> 8.
//  - XCD-aware block swizzle in k_mine16 (t' = (t&7)*260 + t/8; 2080 = 8*260)
//    for A-panel L2 locality.
//  - Mining math/keys unchanged from R20 (proven, absmax 0.0).

typedef __attribute__((ext_vector_type(8))) short short8;
typedef __attribute__((ext_vector_type(4))) float floatx4;

#define B_N 8192
#define D_K 256

__device__ __forceinline__ unsigned short f2bf_rne(float f) {
  unsigned u = __float_as_uint(f);
  u += 0x7FFFu + ((u >> 16) & 1u);
  return (unsigned short)(u >> 16);
}

// DPP helper: row_shr:N — lane i gets lane i-N within its 16-lane row; lanes
// with out-of-row source keep x (old), identity for max/min. Reduction
// accumulates into the TOP lane (l15==15).
#define DPP_SHR(x, CTRL) \
  ((unsigned)__builtin_amdgcn_update_dpp((int)(x), (int)(x), (CTRL), 0xF, 0xF, false))

// ---- fused stable counting sort (one block, 1024 threads, 8 labels each) ----
// perm[pos] = original index; labp[pos] = label (sorted non-decreasing).
__global__ __launch_bounds__(1024) void k_sort(const int* __restrict__ lab,
                                               int* __restrict__ perm,
                                               int* __restrict__ labp,
                                               float* __restrict__ sum,
                                               int* __restrict__ cnt,
                                               int* __restrict__ done) {
  __shared__ int wtot[16][8];   // per-wave class totals
  __shared__ int wbase[16][8];  // exclusive prefix over waves, per class
  __shared__ int ctot[8];       // class totals
  __shared__ int cbase[8];      // class bases
  const int tid = threadIdx.x, lane = tid & 63, w = tid >> 6;

  int l[8], pre[8];
  int lcnt[8] = {0, 0, 0, 0, 0, 0, 0, 0};
#pragma unroll
  for (int k = 0; k < 8; ++k) {
    l[k] = lab[tid * 8 + k] & 7;
    pre[k] = lcnt[l[k]]++;
  }
  // inclusive scan of per-thread counts across the 64 lanes, per class
  int v[8];
#pragma unroll
  for (int c = 0; c < 8; ++c) v[c] = lcnt[c];
  for (int d = 1; d < 64; d <<= 1) {
#pragma unroll
    for (int c = 0; c < 8; ++c) {
      int t = __shfl_up(v[c], d, 64);
      if (lane >= d) v[c] += t;
    }
  }
  int lex[8];
#pragma unroll
  for (int c = 0; c < 8; ++c) lex[c] = v[c] - lcnt[c];   // lane-exclusive
  if (lane == 63) {
#pragma unroll
    for (int c = 0; c < 8; ++c) wtot[w][c] = v[c];
  }
  __syncthreads();
  if (tid < 8) {                 // thread c: exclusive prefix over 16 waves
    int acc = 0;
    for (int ww = 0; ww < 16; ++ww) { wbase[ww][tid] = acc; acc += wtot[ww][tid]; }
    ctot[tid] = acc;
  }
  __syncthreads();
  if (tid == 0) {
    int acc = 0;
    for (int c = 0; c < 8; ++c) { cbase[c] = acc; acc += ctot[c]; }
    *sum = 0.f; *cnt = 0; *done = 0;
  }
  __syncthreads();
#pragma unroll
  for (int k = 0; k < 8; ++k) {
    int c = l[k];
    int pos = cbase[c] + wbase[w][c] + lex[c] + pre[k];
    perm[pos] = tid * 8 + k;
    labp[pos] = c;
  }
}

// ---- split to bf16 fragment-major (PERMUTED rows) + quantized row norms ----
// Tile (16 rows x 32 k) = 512 ushorts at [tile_row][tk][lane*8+j]:
// lane = quad*16 + m, row = 16*tile_row + m, k = 32*tk + quad*8 + j.
__global__ void k_split(const float* __restrict__ x, const int* __restrict__ perm,
                        unsigned short* __restrict__ xhf,
                        float* __restrict__ sqq) {
  __shared__ float sw[64];
  const int tid  = threadIdx.x;
  const int lane = tid & 63;
  const int w    = tid >> 6;
  const int b    = blockIdx.x;        // tile_row
  const int m    = lane & 15;
  const int quad = lane >> 4;
  const int row  = b * 16 + m;        // permuted row
  const int rsrc = perm[row];         // original row

  float s = 0.f;
#pragma unroll
  for (int h = 0; h < 2; ++h) {
    int tk = w + h * 4;
    int kk = tk * 32 + quad * 8;
    float4 f0 = *reinterpret_cast<const float4*>(x + (size_t)rsrc * D_K + kk);
    float4 f1 = *reinterpret_cast<const float4*>(x + (size_t)rsrc * D_K + kk + 4);
    s += f0.x * f0.x + f0.y * f0.y + f0.z * f0.z + f0.w * f0.w;
    s += f1.x * f1.x + f1.y * f1.y + f1.z * f1.z + f1.w * f1.w;
    ushort4 lo, hi;
    lo.x = f2bf_rne(f0.x); lo.y = f2bf_rne(f0.y); lo.z = f2bf_rne(f0.z); lo.w = f2bf_rne(f0.w);
    hi.x = f2bf_rne(f1.x); hi.y = f2bf_rne(f1.y); hi.z = f2bf_rne(f1.z); hi.w = f2bf_rne(f1.w);
    size_t o = ((size_t)b * 8 + tk) * 512 + lane * 8;
    *reinterpret_cast<ushort4*>(xhf + o)     = lo;
    *reinterpret_cast<ushort4*>(xhf + o + 4) = hi;
  }
  s += __shfl_xor(s, 16);
  s += __shfl_xor(s, 32);
  if (quad == 0) sw[w * 16 + m] = s;
  __syncthreads();
  if (tid < 16) {
    int i = b * 16 + tid;
    float t = sw[tid] + sw[16 + tid] + sw[32 + tid] + sw[48 + tid];
    sqq[i] = fmaf(t, 128.f, 262144.f);   // pre-quantized for key calc
  }
}

// ---- specialized mining tail: MODE 0 = pure-neg, 1 = pure-pos, 2 = mixed ----
// 16 rows/lane-group (mt=4): r = mt*4+reg -> ir = i0 + mt*16 + quad*4 + reg.
template <int MODE>
__device__ __forceinline__ void mine_tail(
    const floatx4* acc, const int* __restrict__ labp, const float* __restrict__ sqq,
    int i0, int bi, int bj, int w, int lane,
    unsigned* jbp, unsigned* jbn, unsigned* ibp, unsigned* ibn,
    unsigned* __restrict__ ppart, unsigned* __restrict__ npart) {
  const int wj = w & 1;
  const int quad = lane >> 4, l15 = lane & 15;

  float sqi[16];
#pragma unroll
  for (int r = 0; r < 16; ++r)
    sqi[r] = sqq[i0 + (r >> 2) * 16 + quad * 4 + (r & 3)];

  unsigned long long lip = 0ull;
  if (MODE == 2) {
#pragma unroll
    for (int r = 0; r < 16; ++r) {
      int ir = i0 + (r >> 2) * 16 + quad * 4 + (r & 3);
      lip |= (unsigned long long)((unsigned)labp[ir] & 0xFu) << (r * 4);
    }
  }

  unsigned pkey[16], nkey[16];
#pragma unroll
  for (int r = 0; r < 16; ++r) { pkey[r] = 0u; nkey[r] = 0xFFFFFFFFu; }

#pragma unroll
  for (int nt = 0; nt < 4; ++nt) {
    const int      j  = bj * 128 + wj * 64 + nt * 16 + l15;
    const float    sj = sqq[j];
    const unsigned jl = (MODE == 2) ? ((unsigned)labp[j] & 0xFu) : 0u;
    unsigned jp = 0u, jn = 0xFFFFFFFFu;
#pragma unroll
    for (int r = 0; r < 16; ++r) {
      float dot = acc[(r >> 2) * 4 + nt][r & 3];
      int   ir  = i0 + (r >> 2) * 16 + quad * 4 + (r & 3);
      unsigned keyi = ((unsigned)fmaf(-256.f, dot, sj) << 13) | (unsigned)j;
      unsigned keyj = ((unsigned)fmaf(-256.f, dot, sqi[r]) << 13) | (unsigned)ir;
      if (MODE == 2) {
        bool eq = (jl == (unsigned)((lip >> (r * 4)) & 0xFull));
        unsigned pci = eq ? keyi : 0u;
        unsigned nci = eq ? 0xFFFFFFFFu : keyi;
        pkey[r] = pkey[r] > pci ? pkey[r] : pci;
        nkey[r] = nkey[r] < nci ? nkey[r] : nci;
        unsigned pcj = eq ? keyj : 0u;
        unsigned ncj = eq ? 0xFFFFFFFFu : keyj;
        jp = jp > pcj ? jp : pcj;
        jn = jn < ncj ? jn : ncj;
      } else if (MODE == 1) {
        pkey[r] = pkey[r] > keyi ? pkey[r] : keyi;
        jp = jp > keyj ? jp : keyj;
      } else {
        nkey[r] = nkey[r] < keyi ? nkey[r] : keyi;
        jn = jn < keyj ? jn : keyj;
      }
    }
    // reduce j-side across the 4 quads sharing this j, park in LDS
#pragma unroll
    for (int m = 16; m < 64; m <<= 1) {
      if (MODE != 0) { unsigned op = (unsigned)__shfl_xor((int)jp, m); jp = jp > op ? jp : op; }
      if (MODE != 1) { unsigned on = (unsigned)__shfl_xor((int)jn, m); jn = jn < on ? jn : on; }
    }
    if (quad == 0) {
      jbp[w * 64 + nt * 16 + l15] = (MODE == 0) ? 0u : jp;
      jbn[w * 64 + nt * 16 + l15] = (MODE == 1) ? 0xFFFFFFFFu : jn;
    }
  }

  // i-side: 16-lane DPP row_shr butterfly; result lands in l15==15.
#pragma unroll
  for (int r = 0; r < 16; ++r) {
    if (MODE != 0) { unsigned tp = DPP_SHR(pkey[r], 0x118); pkey[r] = pkey[r] > tp ? pkey[r] : tp; }
    if (MODE != 1) { unsigned tn = DPP_SHR(nkey[r], 0x118); nkey[r] = nkey[r] < tn ? nkey[r] : tn; }
  }
#pragma unroll
  for (int r = 0; r < 16; ++r) {
    if (MODE != 0) { unsigned tp = DPP_SHR(pkey[r], 0x114); pkey[r] = pkey[r] > tp ? pkey[r] : tp; }
    if (MODE != 1) { unsigned tn = DPP_SHR(nkey[r], 0x114); nkey[r] = nkey[r] < tn ? nkey[r] : tn; }
  }
#pragma unroll
  for (int r = 0; r < 16; ++r) {
    if (MODE != 0) { unsigned tp = DPP_SHR(pkey[r], 0x112); pkey[r] = pkey[r] > tp ? pkey[r] : tp; }
    if (MODE != 1) { unsigned tn = DPP_SHR(nkey[r], 0x112); nkey[r] = nkey[r] < tn ? nkey[r] : tn; }
  }
#pragma unroll
  for (int r = 0; r < 16; ++r) {
    if (MODE != 0) { unsigned tp = DPP_SHR(pkey[r], 0x111); pkey[r] = pkey[r] > tp ? pkey[r] : tp; }
    if (MODE != 1) { unsigned tn = DPP_SHR(nkey[r], 0x111); nkey[r] = nkey[r] < tn ? nkey[r] : tn; }
  }
  // park i-side row keys (64 per wave) in LDS for the wj-pair combine
#pragma unroll
  for (int r = 0; r < 16; ++r) {
    if (l15 == 15) {
      int row = (r >> 2) * 16 + quad * 4 + (r & 3);   // 0..63 within wave band
      ibp[w * 64 + row] = (MODE == 0) ? 0u : pkey[r];
      ibn[w * 64 + row] = (MODE == 1) ? 0xFFFFFFFFu : nkey[r];
    }
  }

  __syncthreads();
  // publish phase, 64-slot scheme (slot = opposite block id):
  //  waves 0,2: i-side — combine wj pair (2*half, 2*half+1), slot bj,
  //             rows bi*128 + half*64 + lane.
  //  waves 1,3: j-side — combine wi pair (jh, jh+2), slot bi,
  //             cols bj*128 + jh*64 + lane. Diagonal skipped (i-side covers).
  if ((w & 1) == 0) {
    const int half = w >> 1;
    unsigned p  = ibp[(2 * half) * 64 + lane];
    unsigned p2 = ibp[(2 * half + 1) * 64 + lane];
    unsigned n  = ibn[(2 * half) * 64 + lane];
    unsigned n2 = ibn[(2 * half + 1) * 64 + lane];
    p = p > p2 ? p : p2;
    n = n < n2 ? n : n2;
    int ir = bi * 128 + half * 64 + lane;
    size_t idx = (size_t)bj * B_N + ir;
    ppart[idx] = p;
    npart[idx] = n;
  } else if (bi != bj) {
    const int jh = w >> 1;                  // w1 -> wj half 0, w3 -> half 1
    unsigned p  = jbp[jh * 64 + lane];
    unsigned p2 = jbp[(jh + 2) * 64 + lane];
    unsigned n  = jbn[jh * 64 + lane];
    unsigned n2 = jbn[(jh + 2) * 64 + lane];
    p = p > p2 ? p : p2;
    n = n < n2 ? n : n2;
    int j = bj * 128 + jh * 64 + lane;
    size_t idx = (size_t)bi * B_N + j;
    ppart[idx] = p;
    npart[idx] = n;
  }
}

// ---- MFMA Gram + two-sided mining, 4 waves/block, 64x64 per wave ----
__global__ __launch_bounds__(256, 3) void k_mine16(
    const unsigned short* __restrict__ xhf, const int* __restrict__ labp,
    const float* __restrict__ sqq,
    unsigned* __restrict__ ppart, unsigned* __restrict__ npart) {
  __shared__ unsigned jbp[4 * 64], jbn[4 * 64];  // j-side per-wave partials
  __shared__ unsigned ibp[4 * 64], ibn[4 * 64];  // i-side per-wave row keys

  // XCD-aware swizzle: 2080 = 8 * 260, keep each XCD on a contiguous t-range
  int t = blockIdx.x;
  t = (t & 7) * 260 + (t >> 3);

  // decode linear t -> (bi, bj), bi <= bj, over 64x64 block grid
  int bi = (int)(64.5f - sqrtf(64.5f * 64.5f - 2.f * (float)t));
  int b0 = 64 * bi - (bi * (bi - 1)) / 2;
  if (t < b0) { bi--; b0 = 64 * bi - (bi * (bi - 1)) / 2; }
  else {
    int b1 = 64 * (bi + 1) - ((bi + 1) * bi) / 2;
    if (t >= b1) { bi++; b0 = b1; }
  }
  const int bj = bi + (t - b0);

  const int tid  = threadIdx.x;
  const int lane = tid & 63;
  const int w    = tid >> 6;          // 0..3
  const int wi   = w >> 1;            // 0..1 : 64-row half of the band
  const int wj   = w & 1;             // 0..1 : 64-col half
  const int i0   = bi * 128 + wi * 64;

  // tile classification from sorted-label range endpoints (block-uniform)
  const int la0 = labp[bi * 128];
  const int la1 = labp[bi * 128 + 127];
  const int lb0 = labp[bj * 128];
  const int lb1 = labp[bj * 128 + 127];

  // fragment-major offsets (ushort units): row-block rb -> rb*4096 + tk*512
  const unsigned aoff = (unsigned)(bi * 8 + wi * 4) * 4096u + (unsigned)lane * 8u;
  const unsigned boff = (unsigned)(bj * 8 + wj * 4) * 4096u + (unsigned)lane * 8u;

  floatx4 acc[16];
#pragma unroll
  for (int q = 0; q < 16; ++q) acc[q] = (floatx4)0.f;

#pragma unroll
  for (int tk = 0; tk < 8; ++tk) {
    short8 Bf[4];
#pragma unroll
    for (int nt = 0; nt < 4; ++nt)
      Bf[nt] = *reinterpret_cast<const short8*>(xhf + boff + (unsigned)(nt * 4096 + tk * 512));
    short8 Af[4];
#pragma unroll
    for (int mt = 0; mt < 4; ++mt)
      Af[mt] = *reinterpret_cast<const short8*>(xhf + aoff + (unsigned)(mt * 4096 + tk * 512));
#pragma unroll
    for (int mt = 0; mt < 4; ++mt)
#pragma unroll
      for (int nt = 0; nt < 4; ++nt)
        acc[mt * 4 + nt] = __builtin_amdgcn_mfma_f32_16x16x32_bf16(
            Af[mt], Bf[nt], acc[mt * 4 + nt], 0, 0, 0);
  }

  if (la1 < lb0 || lb1 < la0) {
    mine_tail<0>(acc, labp, sqq, i0, bi, bj, w, lane, jbp, jbn, ibp, ibn, ppart, npart);
  } else if (la0 == lb1 && la1 == lb0) {   // sorted => all four labels equal
    mine_tail<1>(acc, labp, sqq, i0, bi, bj, w, lane, jbp, jbn, ibp, ibn, ppart, npart);
  } else {
    mine_tail<2>(acc, labp, sqq, i0, bi, bj, w, lane, jbp, jbn, ibp, ibn, ppart, npart);
  }
}

// ---- slot-reduce (64 slots) + exact fp32 triplet distances + loss ----
__global__ void k_finish(const float* __restrict__ x, const int* __restrict__ perm,
                         const unsigned* __restrict__ ppart,
                         const unsigned* __restrict__ npart,
                         float* __restrict__ sum, int* __restrict__ cnt,
                         int* __restrict__ done, float* __restrict__ out) {
  __shared__ unsigned spk[32], snk[32];
  __shared__ float ssum[4];
  __shared__ int   scnt[4];
  const int tid = threadIdx.x;
  const int a0  = blockIdx.x * 32;

  if (tid < 32) { spk[tid] = 0u; snk[tid] = 0xFFFFFFFFu; }
  __syncthreads();

  {
    const int a    = a0 + (tid & 31);
    const int part = tid >> 5;           // 0..7 -> slots part*8 .. part*8+7
    unsigned p = 0u, n = 0xFFFFFFFFu;
#pragma unroll
    for (int s = 0; s < 8; ++s) {
      size_t idx = (size_t)(part * 8 + s) * B_N + a;
      unsigned pv = ppart[idx];
      unsigned nv = npart[idx];
      p = p > pv ? p : pv;
      n = n < nv ? n : nv;
    }
    atomicMax(&spk[tid & 31], p);        // LDS atomics: cheap, 8-way
    atomicMin(&snk[tid & 31], n);
  }
  __syncthreads();

  const int w = tid >> 6, lane = tid & 63;
  float lsum = 0.f; int lcnt = 0;
#pragma unroll
  for (int it = 0; it < 8; ++it) {
    int al = w * 8 + it;                 // 0..31
    int a  = a0 + al;                    // permuted anchor
    unsigned p = spk[al];
    unsigned n = snk[al];
    bool valid = (p != 0u) && (n != 0xFFFFFFFFu);
    int  pidx = valid ? (int)(p & 8191u) : 0;
    int  nidx = valid ? (int)(n & 8191u) : 0;
    int  ra = perm[a], rp = perm[pidx], rn = perm[nidx];

    float4 xa = *reinterpret_cast<const float4*>(x + (size_t)ra * D_K + lane * 4);
    float4 xp = *reinterpret_cast<const float4*>(x + (size_t)rp * D_K + lane * 4);
    float4 xn = *reinterpret_cast<const float4*>(x + (size_t)rn * D_K + lane * 4);
    float dx, sp = 0.f, sn = 0.f;
    dx = xa.x - xp.x + 1e-6f; sp = fmaf(dx, dx, sp);
    dx = xa.y - xp.y + 1e-6f; sp = fmaf(dx, dx, sp);
    dx = xa.z - xp.z + 1e-6f; sp = fmaf(dx, dx, sp);
    dx = xa.w - xp.w + 1e-6f; sp = fmaf(dx, dx, sp);
    dx = xa.x - xn.x + 1e-6f; sn = fmaf(dx, dx, sn);
    dx = xa.y - xn.y + 1e-6f; sn = fmaf(dx, dx, sn);
    dx = xa.z - xn.z + 1e-6f; sn = fmaf(dx, dx, sn);
    dx = xa.w - xn.w + 1e-6f; sn = fmaf(dx, dx, sn);
#pragma unroll
    for (int o = 32; o > 0; o >>= 1) {
      sp += __shfl_down(sp, o, 64);
      sn += __shfl_down(sn, o, 64);
    }
    if (lane == 0 && valid) {
      float per = sqrtf(sp) - sqrtf(sn) + 0.3f;
      if (per > 0.f) lsum += per;
      lcnt += 1;
    }
  }
  if (lane == 0) { ssum[w] = lsum; scnt[w] = lcnt; }
  __syncthreads();
  if (tid == 0) {
    atomicAdd(sum, ssum[0] + ssum[1] + ssum[2] + ssum[3]);
    atomicAdd(cnt, scnt[0] + scnt[1] + scnt[2] + scnt[3]);
    __threadfence();
    int prev = atomicAdd(done, 1);
    if (prev == gridDim.x - 1) {
      float s = atomicAdd(sum, 0.f);
      int   cc = atomicAdd(cnt, 0);
      if (cc < 1) cc = 1;
      out[0] = s / (float)cc;
    }
  }
}

extern "C" void kernel_launch(void* const* d_in, const int* in_sizes, int n_in,
                              void* d_out, int out_size, void* d_ws, size_t ws_size,
                              hipStream_t stream) {
  const float* x   = (const float*)d_in[0];
  const int*   lab = (const int*)d_in[1];
  float*       out = (float*)d_out;

  char* ws = (char*)d_ws;
  unsigned short* xhf = (unsigned short*)ws;                      // 4 MB
  int* perm      = (int*)(ws + (size_t)4096 * 1024);              // 32 KB
  int* labp      = (int*)(ws + (size_t)4096 * 1024 + 32768);      // 32 KB
  float* sqq = (float*)(ws + (size_t)4608 * 1024);                // 32 KB
  char*  pb = ws + (size_t)4608 * 1024 + 65536;
  size_t seg = (size_t)64 * B_N * 4;                              // 2 MB each
  unsigned* ppart = (unsigned*)(pb);
  unsigned* npart = (unsigned*)(pb + seg);
  float* sum  = (float*)(pb + 2 * seg);
  int*   cnt  = (int*)(sum + 1);
  int*   done = (int*)(sum + 2);

  k_sort<<<1, 1024, 0, stream>>>(lab, perm, labp, sum, cnt, done);
  k_split<<<B_N / 16, 256, 0, stream>>>(x, perm, xhf, sqq);
  k_mine16<<<2080, 256, 0, stream>>>(xhf, labp, sqq, ppart, npart);
  k_finish<<<B_N / 32, 256, 0, stream>>>(x, perm, ppart, npart, sum, cnt, done, out);
}

// Round 6
// 114.431 us; speedup vs baseline: 1.0577x; 1.0577x over previous
//
#include <hip/hip_runtime.h>
#include <math.h>

// EnhancedTripletLoss, B=8192, D=256, 8 classes.
// R22: revert R21 regressions + LDS-staged mine.
//  - k_sort (single-block, serial bubble) reverted to parallel k_hist+k_perm
//    (R19/R20 proven). XCD swizzle dropped (xhf is L2-resident; swizzle costs
//    in the cache-fit regime).
//  - k_mine16 is L2-delivery-bound (256 KB/tile, panels read 2x by wave
//    pairs). New: per-tk double-buffered LDS staging via global_load_lds
//    (16B width, linear dest = fragment-major layout). L2 traffic halves to
//    128 KB/tile. 32 KB stage dbuf + 4 KB partials LDS.
//  - 64-slot scheme + mine_tail + k_finish unchanged from R21 (passed).

typedef __attribute__((ext_vector_type(8))) short short8;
typedef __attribute__((ext_vector_type(4))) float floatx4;

#define B_N 8192
#define D_K 256

__device__ __forceinline__ unsigned short f2bf_rne(float f) {
  unsigned u = __float_as_uint(f);
  u += 0x7FFFu + ((u >> 16) & 1u);
  return (unsigned short)(u >> 16);
}

// async global->LDS, 16 B/lane. LDS dest is wave-uniform base + lane*16;
// global src is per-lane. Our fragment-major layout matches exactly.
__device__ __forceinline__ void gl_lds16(const unsigned short* g, unsigned short* l) {
  __builtin_amdgcn_global_load_lds(
      (const __attribute__((address_space(1))) unsigned int*)g,
      (__attribute__((address_space(3))) unsigned int*)l, 16, 0, 0);
}

// DPP helper: row_shr:N — lane i gets lane i-N within its 16-lane row; lanes
// with out-of-row source keep x (old), identity for max/min. Reduction
// accumulates into the TOP lane (l15==15).
#define DPP_SHR(x, CTRL) \
  ((unsigned)__builtin_amdgcn_update_dpp((int)(x), (int)(x), (CTRL), 0xF, 0xF, false))

// ---- counting-sort pass 1: per-256-chunk class histogram ----
__global__ void k_hist(const int* __restrict__ lab, int* __restrict__ chunkhist,
                       float* __restrict__ sum, int* __restrict__ cnt,
                       int* __restrict__ done) {
  __shared__ int h[8];
  const int tid = threadIdx.x, b = blockIdx.x;
  if (tid < 8) h[tid] = 0;
  __syncthreads();
  atomicAdd(&h[lab[b * 256 + tid] & 7], 1);
  __syncthreads();
  if (tid < 8) chunkhist[b * 8 + tid] = h[tid];
  if (b == 0 && tid == 0) { *sum = 0.f; *cnt = 0; *done = 0; }
}

// ---- counting-sort pass 2: deterministic stable scatter ----
// perm[pos] = original index; labp[pos] = label (sorted non-decreasing).
__global__ void k_perm(const int* __restrict__ lab, const int* __restrict__ chunkhist,
                       int* __restrict__ perm, int* __restrict__ labp) {
  __shared__ int ch[256];       // all 32 chunk hists
  __shared__ int base[8];       // global scatter base for this chunk, per class
  __shared__ int wcnt[4][8];    // per-wave per-class counts
  const int tid = threadIdx.x, b = blockIdx.x;
  ch[tid] = chunkhist[tid];
  __syncthreads();
  if (tid < 8) {
    const int c = tid;
    int acc = 0;
    for (int cc = 0; cc < c; ++cc)
      for (int k = 0; k < 32; ++k) acc += ch[k * 8 + cc];   // classes before c
    for (int k = 0; k < b; ++k) acc += ch[k * 8 + c];       // chunks before b
    base[c] = acc;
  }
  const int i    = b * 256 + tid;
  const int myc  = lab[i] & 7;
  const int lane = tid & 63, w = tid >> 6;
  unsigned long long bal[8];
#pragma unroll
  for (int c = 0; c < 8; ++c) bal[c] = __ballot(myc == c);
  if (lane == 0) {
#pragma unroll
    for (int c = 0; c < 8; ++c) wcnt[w][c] = (int)__popcll(bal[c]);
  }
  __syncthreads();
  int rank = (int)__popcll(bal[myc] & ((1ull << lane) - 1ull));
  for (int ww = 0; ww < w; ++ww) rank += wcnt[ww][myc];
  const int pos = base[myc] + rank;
  perm[pos] = i;
  labp[pos] = myc;
}

// ---- split to bf16 fragment-major (PERMUTED rows) + quantized row norms ----
// Tile (16 rows x 32 k) = 512 ushorts at [tile_row][tk][lane*8+j]:
// lane = quad*16 + m, row = 16*tile_row + m, k = 32*tk + quad*8 + j.
__global__ void k_split(const float* __restrict__ x, const int* __restrict__ perm,
                        unsigned short* __restrict__ xhf,
                        float* __restrict__ sqq) {
  __shared__ float sw[64];
  const int tid  = threadIdx.x;
  const int lane = tid & 63;
  const int w    = tid >> 6;
  const int b    = blockIdx.x;        // tile_row
  const int m    = lane & 15;
  const int quad = lane >> 4;
  const int row  = b * 16 + m;        // permuted row
  const int rsrc = perm[row];         // original row

  float s = 0.f;
#pragma unroll
  for (int h = 0; h < 2; ++h) {
    int tk = w + h * 4;
    int kk = tk * 32 + quad * 8;
    float4 f0 = *reinterpret_cast<const float4*>(x + (size_t)rsrc * D_K + kk);
    float4 f1 = *reinterpret_cast<const float4*>(x + (size_t)rsrc * D_K + kk + 4);
    s += f0.x * f0.x + f0.y * f0.y + f0.z * f0.z + f0.w * f0.w;
    s += f1.x * f1.x + f1.y * f1.y + f1.z * f1.z + f1.w * f1.w;
    ushort4 lo, hi;
    lo.x = f2bf_rne(f0.x); lo.y = f2bf_rne(f0.y); lo.z = f2bf_rne(f0.z); lo.w = f2bf_rne(f0.w);
    hi.x = f2bf_rne(f1.x); hi.y = f2bf_rne(f1.y); hi.z = f2bf_rne(f1.z); hi.w = f2bf_rne(f1.w);
    size_t o = ((size_t)b * 8 + tk) * 512 + lane * 8;
    *reinterpret_cast<ushort4*>(xhf + o)     = lo;
    *reinterpret_cast<ushort4*>(xhf + o + 4) = hi;
  }
  s += __shfl_xor(s, 16);
  s += __shfl_xor(s, 32);
  if (quad == 0) sw[w * 16 + m] = s;
  __syncthreads();
  if (tid < 16) {
    int i = b * 16 + tid;
    float t = sw[tid] + sw[16 + tid] + sw[32 + tid] + sw[48 + tid];
    sqq[i] = fmaf(t, 128.f, 262144.f);   // pre-quantized for key calc
  }
}

// ---- specialized mining tail: MODE 0 = pure-neg, 1 = pure-pos, 2 = mixed ----
// 16 rows/lane-group (mt=4): r = mt*4+reg -> ir = i0 + mt*16 + quad*4 + reg.
template <int MODE>
__device__ __forceinline__ void mine_tail(
    const floatx4* acc, const int* __restrict__ labp, const float* __restrict__ sqq,
    int i0, int bi, int bj, int w, int lane,
    unsigned* jbp, unsigned* jbn, unsigned* ibp, unsigned* ibn,
    unsigned* __restrict__ ppart, unsigned* __restrict__ npart) {
  const int wj = w & 1;
  const int quad = lane >> 4, l15 = lane & 15;

  float sqi[16];
#pragma unroll
  for (int r = 0; r < 16; ++r)
    sqi[r] = sqq[i0 + (r >> 2) * 16 + quad * 4 + (r & 3)];

  unsigned long long lip = 0ull;
  if (MODE == 2) {
#pragma unroll
    for (int r = 0; r < 16; ++r) {
      int ir = i0 + (r >> 2) * 16 + quad * 4 + (r & 3);
      lip |= (unsigned long long)((unsigned)labp[ir] & 0xFu) << (r * 4);
    }
  }

  unsigned pkey[16], nkey[16];
#pragma unroll
  for (int r = 0; r < 16; ++r) { pkey[r] = 0u; nkey[r] = 0xFFFFFFFFu; }

#pragma unroll
  for (int nt = 0; nt < 4; ++nt) {
    const int      j  = bj * 128 + wj * 64 + nt * 16 + l15;
    const float    sj = sqq[j];
    const unsigned jl = (MODE == 2) ? ((unsigned)labp[j] & 0xFu) : 0u;
    unsigned jp = 0u, jn = 0xFFFFFFFFu;
#pragma unroll
    for (int r = 0; r < 16; ++r) {
      float dot = acc[(r >> 2) * 4 + nt][r & 3];
      int   ir  = i0 + (r >> 2) * 16 + quad * 4 + (r & 3);
      unsigned keyi = ((unsigned)fmaf(-256.f, dot, sj) << 13) | (unsigned)j;
      unsigned keyj = ((unsigned)fmaf(-256.f, dot, sqi[r]) << 13) | (unsigned)ir;
      if (MODE == 2) {
        bool eq = (jl == (unsigned)((lip >> (r * 4)) & 0xFull));
        unsigned pci = eq ? keyi : 0u;
        unsigned nci = eq ? 0xFFFFFFFFu : keyi;
        pkey[r] = pkey[r] > pci ? pkey[r] : pci;
        nkey[r] = nkey[r] < nci ? nkey[r] : nci;
        unsigned pcj = eq ? keyj : 0u;
        unsigned ncj = eq ? 0xFFFFFFFFu : keyj;
        jp = jp > pcj ? jp : pcj;
        jn = jn < ncj ? jn : ncj;
      } else if (MODE == 1) {
        pkey[r] = pkey[r] > keyi ? pkey[r] : keyi;
        jp = jp > keyj ? jp : keyj;
      } else {
        nkey[r] = nkey[r] < keyi ? nkey[r] : keyi;
        jn = jn < keyj ? jn : keyj;
      }
    }
    // reduce j-side across the 4 quads sharing this j, park in LDS
#pragma unroll
    for (int m = 16; m < 64; m <<= 1) {
      if (MODE != 0) { unsigned op = (unsigned)__shfl_xor((int)jp, m); jp = jp > op ? jp : op; }
      if (MODE != 1) { unsigned on = (unsigned)__shfl_xor((int)jn, m); jn = jn < on ? jn : on; }
    }
    if (quad == 0) {
      jbp[w * 64 + nt * 16 + l15] = (MODE == 0) ? 0u : jp;
      jbn[w * 64 + nt * 16 + l15] = (MODE == 1) ? 0xFFFFFFFFu : jn;
    }
  }

  // i-side: 16-lane DPP row_shr butterfly; result lands in l15==15.
#pragma unroll
  for (int r = 0; r < 16; ++r) {
    if (MODE != 0) { unsigned tp = DPP_SHR(pkey[r], 0x118); pkey[r] = pkey[r] > tp ? pkey[r] : tp; }
    if (MODE != 1) { unsigned tn = DPP_SHR(nkey[r], 0x118); nkey[r] = nkey[r] < tn ? nkey[r] : tn; }
  }
#pragma unroll
  for (int r = 0; r < 16; ++r) {
    if (MODE != 0) { unsigned tp = DPP_SHR(pkey[r], 0x114); pkey[r] = pkey[r] > tp ? pkey[r] : tp; }
    if (MODE != 1) { unsigned tn = DPP_SHR(nkey[r], 0x114); nkey[r] = nkey[r] < tn ? nkey[r] : tn; }
  }
#pragma unroll
  for (int r = 0; r < 16; ++r) {
    if (MODE != 0) { unsigned tp = DPP_SHR(pkey[r], 0x112); pkey[r] = pkey[r] > tp ? pkey[r] : tp; }
    if (MODE != 1) { unsigned tn = DPP_SHR(nkey[r], 0x112); nkey[r] = nkey[r] < tn ? nkey[r] : tn; }
  }
#pragma unroll
  for (int r = 0; r < 16; ++r) {
    if (MODE != 0) { unsigned tp = DPP_SHR(pkey[r], 0x111); pkey[r] = pkey[r] > tp ? pkey[r] : tp; }
    if (MODE != 1) { unsigned tn = DPP_SHR(nkey[r], 0x111); nkey[r] = nkey[r] < tn ? nkey[r] : tn; }
  }
  // park i-side row keys (64 per wave) in LDS for the wj-pair combine
#pragma unroll
  for (int r = 0; r < 16; ++r) {
    if (l15 == 15) {
      int row = (r >> 2) * 16 + quad * 4 + (r & 3);   // 0..63 within wave band
      ibp[w * 64 + row] = (MODE == 0) ? 0u : pkey[r];
      ibn[w * 64 + row] = (MODE == 1) ? 0xFFFFFFFFu : nkey[r];
    }
  }

  __syncthreads();
  // publish phase, 64-slot scheme (slot = opposite block id):
  //  waves 0,2: i-side — combine wj pair (2*half, 2*half+1), slot bj,
  //             rows bi*128 + half*64 + lane.
  //  waves 1,3: j-side — combine wi pair (jh, jh+2), slot bi,
  //             cols bj*128 + jh*64 + lane. Diagonal skipped (i-side covers).
  if ((w & 1) == 0) {
    const int half = w >> 1;
    unsigned p  = ibp[(2 * half) * 64 + lane];
    unsigned p2 = ibp[(2 * half + 1) * 64 + lane];
    unsigned n  = ibn[(2 * half) * 64 + lane];
    unsigned n2 = ibn[(2 * half + 1) * 64 + lane];
    p = p > p2 ? p : p2;
    n = n < n2 ? n : n2;
    int ir = bi * 128 + half * 64 + lane;
    size_t idx = (size_t)bj * B_N + ir;
    ppart[idx] = p;
    npart[idx] = n;
  } else if (bi != bj) {
    const int jh = w >> 1;                  // w1 -> wj half 0, w3 -> half 1
    unsigned p  = jbp[jh * 64 + lane];
    unsigned p2 = jbp[(jh + 2) * 64 + lane];
    unsigned n  = jbn[jh * 64 + lane];
    unsigned n2 = jbn[(jh + 2) * 64 + lane];
    p = p > p2 ? p : p2;
    n = n < n2 ? n : n2;
    int j = bj * 128 + jh * 64 + lane;
    size_t idx = (size_t)bi * B_N + j;
    ppart[idx] = p;
    npart[idx] = n;
  }
}

// ---- MFMA Gram + two-sided mining, 4 waves/block, 64x64 per wave ----
// Per-tk LDS staging: stage[bf][0..7] = A rowblocks (band bi), [8..15] = B
// rowblocks (band bj), 512 ushorts each; double-buffered (32 KB).
__global__ __launch_bounds__(256, 3) void k_mine16(
    const unsigned short* __restrict__ xhf, const int* __restrict__ labp,
    const float* __restrict__ sqq,
    unsigned* __restrict__ ppart, unsigned* __restrict__ npart) {
  __shared__ unsigned short stage[2][16][512];   // 32 KB staging dbuf
  __shared__ unsigned jbp[4 * 64], jbn[4 * 64];  // j-side per-wave partials
  __shared__ unsigned ibp[4 * 64], ibn[4 * 64];  // i-side per-wave row keys

  // decode linear block id -> (bi, bj), bi <= bj, over 64x64 block grid
  int t  = blockIdx.x;
  int bi = (int)(64.5f - sqrtf(64.5f * 64.5f - 2.f * (float)t));
  int b0 = 64 * bi - (bi * (bi - 1)) / 2;
  if (t < b0) { bi--; b0 = 64 * bi - (bi * (bi - 1)) / 2; }
  else {
    int b1 = 64 * (bi + 1) - ((bi + 1) * bi) / 2;
    if (t >= b1) { bi++; b0 = b1; }
  }
  const int bj = bi + (t - b0);

  const int tid  = threadIdx.x;
  const int lane = tid & 63;
  const int w    = tid >> 6;          // 0..3
  const int wi   = w >> 1;            // 0..1 : 64-row half of the band
  const int wj   = w & 1;             // 0..1 : 64-col half
  const int i0   = bi * 128 + wi * 64;

  // tile classification from sorted-label range endpoints (block-uniform)
  const int la0 = labp[bi * 128];
  const int la1 = labp[bi * 128 + 127];
  const int lb0 = labp[bj * 128];
  const int lb1 = labp[bj * 128 + 127];

  // staging sources: wave w stages rowblocks {w, 4+w} of each panel
  const unsigned short* srcA0 = xhf + (size_t)(bi * 8 + w)     * 4096 + lane * 8;
  const unsigned short* srcA1 = xhf + (size_t)(bi * 8 + 4 + w) * 4096 + lane * 8;
  const unsigned short* srcB0 = xhf + (size_t)(bj * 8 + w)     * 4096 + lane * 8;
  const unsigned short* srcB1 = xhf + (size_t)(bj * 8 + 4 + w) * 4096 + lane * 8;

#define STAGE(bf, tk)                                             \
  do {                                                            \
    gl_lds16(srcA0 + (tk) * 512, &stage[bf][w][0]);               \
    gl_lds16(srcA1 + (tk) * 512, &stage[bf][4 + w][0]);           \
    gl_lds16(srcB0 + (tk) * 512, &stage[bf][8 + w][0]);           \
    gl_lds16(srcB1 + (tk) * 512, &stage[bf][12 + w][0]);          \
  } while (0)

  floatx4 acc[16];
#pragma unroll
  for (int q = 0; q < 16; ++q) acc[q] = (floatx4)0.f;

  STAGE(0, 0);
  __syncthreads();                    // drains vmcnt -> stage[0] ready

  int bf = 0;
#pragma unroll
  for (int tk = 0; tk < 8; ++tk) {
    if (tk < 7) STAGE(bf ^ 1, tk + 1);
    short8 Bf[4];
#pragma unroll
    for (int nt = 0; nt < 4; ++nt)
      Bf[nt] = *reinterpret_cast<const short8*>(&stage[bf][8 + wj * 4 + nt][lane * 8]);
    short8 Af[4];
#pragma unroll
    for (int mt = 0; mt < 4; ++mt)
      Af[mt] = *reinterpret_cast<const short8*>(&stage[bf][wi * 4 + mt][lane * 8]);
#pragma unroll
    for (int mt = 0; mt < 4; ++mt)
#pragma unroll
      for (int nt = 0; nt < 4; ++nt)
        acc[mt * 4 + nt] = __builtin_amdgcn_mfma_f32_16x16x32_bf16(
            Af[mt], Bf[nt], acc[mt * 4 + nt], 0, 0, 0);
    __syncthreads();                  // next stage ready + all reads of bf done
    bf ^= 1;
  }
#undef STAGE

  if (la1 < lb0 || lb1 < la0) {
    mine_tail<0>(acc, labp, sqq, i0, bi, bj, w, lane, jbp, jbn, ibp, ibn, ppart, npart);
  } else if (la0 == lb1 && la1 == lb0) {   // sorted => all four labels equal
    mine_tail<1>(acc, labp, sqq, i0, bi, bj, w, lane, jbp, jbn, ibp, ibn, ppart, npart);
  } else {
    mine_tail<2>(acc, labp, sqq, i0, bi, bj, w, lane, jbp, jbn, ibp, ibn, ppart, npart);
  }
}

// ---- slot-reduce (64 slots) + exact fp32 triplet distances + loss ----
__global__ void k_finish(const float* __restrict__ x, const int* __restrict__ perm,
                         const unsigned* __restrict__ ppart,
                         const unsigned* __restrict__ npart,
                         float* __restrict__ sum, int* __restrict__ cnt,
                         int* __restrict__ done, float* __restrict__ out) {
  __shared__ unsigned spk[32], snk[32];
  __shared__ float ssum[4];
  __shared__ int   scnt[4];
  const int tid = threadIdx.x;
  const int a0  = blockIdx.x * 32;

  if (tid < 32) { spk[tid] = 0u; snk[tid] = 0xFFFFFFFFu; }
  __syncthreads();

  {
    const int a    = a0 + (tid & 31);
    const int part = tid >> 5;           // 0..7 -> slots part*8 .. part*8+7
    unsigned p = 0u, n = 0xFFFFFFFFu;
#pragma unroll
    for (int s = 0; s < 8; ++s) {
      size_t idx = (size_t)(part * 8 + s) * B_N + a;
      unsigned pv = ppart[idx];
      unsigned nv = npart[idx];
      p = p > pv ? p : pv;
      n = n < nv ? n : nv;
    }
    atomicMax(&spk[tid & 31], p);        // LDS atomics: cheap, 8-way
    atomicMin(&snk[tid & 31], n);
  }
  __syncthreads();

  const int w = tid >> 6, lane = tid & 63;
  float lsum = 0.f; int lcnt = 0;
#pragma unroll
  for (int it = 0; it < 8; ++it) {
    int al = w * 8 + it;                 // 0..31
    int a  = a0 + al;                    // permuted anchor
    unsigned p = spk[al];
    unsigned n = snk[al];
    bool valid = (p != 0u) && (n != 0xFFFFFFFFu);
    int  pidx = valid ? (int)(p & 8191u) : 0;
    int  nidx = valid ? (int)(n & 8191u) : 0;
    int  ra = perm[a], rp = perm[pidx], rn = perm[nidx];

    float4 xa = *reinterpret_cast<const float4*>(x + (size_t)ra * D_K + lane * 4);
    float4 xp = *reinterpret_cast<const float4*>(x + (size_t)rp * D_K + lane * 4);
    float4 xn = *reinterpret_cast<const float4*>(x + (size_t)rn * D_K + lane * 4);
    float dx, sp = 0.f, sn = 0.f;
    dx = xa.x - xp.x + 1e-6f; sp = fmaf(dx, dx, sp);
    dx = xa.y - xp.y + 1e-6f; sp = fmaf(dx, dx, sp);
    dx = xa.z - xp.z + 1e-6f; sp = fmaf(dx, dx, sp);
    dx = xa.w - xp.w + 1e-6f; sp = fmaf(dx, dx, sp);
    dx = xa.x - xn.x + 1e-6f; sn = fmaf(dx, dx, sn);
    dx = xa.y - xn.y + 1e-6f; sn = fmaf(dx, dx, sn);
    dx = xa.z - xn.z + 1e-6f; sn = fmaf(dx, dx, sn);
    dx = xa.w - xn.w + 1e-6f; sn = fmaf(dx, dx, sn);
#pragma unroll
    for (int o = 32; o > 0; o >>= 1) {
      sp += __shfl_down(sp, o, 64);
      sn += __shfl_down(sn, o, 64);
    }
    if (lane == 0 && valid) {
      float per = sqrtf(sp) - sqrtf(sn) + 0.3f;
      if (per > 0.f) lsum += per;
      lcnt += 1;
    }
  }
  if (lane == 0) { ssum[w] = lsum; scnt[w] = lcnt; }
  __syncthreads();
  if (tid == 0) {
    atomicAdd(sum, ssum[0] + ssum[1] + ssum[2] + ssum[3]);
    atomicAdd(cnt, scnt[0] + scnt[1] + scnt[2] + scnt[3]);
    __threadfence();
    int prev = atomicAdd(done, 1);
    if (prev == gridDim.x - 1) {
      float s = atomicAdd(sum, 0.f);
      int   cc = atomicAdd(cnt, 0);
      if (cc < 1) cc = 1;
      out[0] = s / (float)cc;
    }
  }
}

extern "C" void kernel_launch(void* const* d_in, const int* in_sizes, int n_in,
                              void* d_out, int out_size, void* d_ws, size_t ws_size,
                              hipStream_t stream) {
  const float* x   = (const float*)d_in[0];
  const int*   lab = (const int*)d_in[1];
  float*       out = (float*)d_out;

  char* ws = (char*)d_ws;
  unsigned short* xhf = (unsigned short*)ws;                      // 4 MB
  int* perm      = (int*)(ws + (size_t)4096 * 1024);              // 32 KB
  int* labp      = (int*)(ws + (size_t)4096 * 1024 + 32768);      // 32 KB
  int* chunkhist = (int*)(ws + (size_t)4096 * 1024 + 65536);      // 1 KB
  float* sqq = (float*)(ws + (size_t)4608 * 1024);                // 32 KB
  char*  pb = ws + (size_t)4608 * 1024 + 65536;
  size_t seg = (size_t)64 * B_N * 4;                              // 2 MB each
  unsigned* ppart = (unsigned*)(pb);
  unsigned* npart = (unsigned*)(pb + seg);
  float* sum  = (float*)(pb + 2 * seg);
  int*   cnt  = (int*)(sum + 1);
  int*   done = (int*)(sum + 2);

  k_hist<<<32, 256, 0, stream>>>(lab, chunkhist, sum, cnt, done);
  k_perm<<<32, 256, 0, stream>>>(lab, chunkhist, perm, labp);
  k_split<<<B_N / 16, 256, 0, stream>>>(x, perm, xhf, sqq);
  k_mine16<<<2080, 256, 0, stream>>>(xhf, labp, sqq, ppart, npart);
  k_finish<<<B_N / 32, 256, 0, stream>>>(x, perm, ppart, npart, sum, cnt, done, out);
}